// Round 4
// baseline (445.611 us; speedup 1.0000x reference)
//
#include <hip/hip_runtime.h>

#define NPTS 1048576
#define NCH 32
#define GS 96
#define GV (GS * GS * GS)
#define DIN 68
#define HD 128
#define TILE_PTS 32
#define NTILES (NPTS / TILE_PTS)   // 32768 exact, no tail
#define NBLK 256
#define NTHR 768                   // 12 waves/block, 1 block/CU -> 3 waves/SIMD
#define WAVES_TOT (NBLK * 12)

typedef __bf16 bf16x8 __attribute__((ext_vector_type(8)));
typedef float f32x4 __attribute__((ext_vector_type(4)));
typedef float f32x2 __attribute__((ext_vector_type(2)));

__device__ __forceinline__ unsigned int f2bf(float f) {
  unsigned int u = __float_as_uint(f);
  return (u + 0x7fffu + ((u >> 16) & 1u)) >> 16;  // RNE
}
__device__ __forceinline__ unsigned int pkbf(float a, float b) {
#if __has_builtin(__builtin_amdgcn_cvt_pk_bf16_f32)
  return __builtin_bit_cast(unsigned int, __builtin_amdgcn_cvt_pk_bf16_f32(a, b));
#else
  return f2bf(a) | (f2bf(b) << 16);
#endif
}

// ---------------- grid transpose: [32][96^3] f32 -> [96^3][32] bf16 ----------------
__global__ __launch_bounds__(256) void k_prep_grid(const float* __restrict__ src,
                                                   unsigned int* __restrict__ dst) {
  __shared__ unsigned int tile[256 * 17];
  const int tid = threadIdx.x;
  const long vb = (long)blockIdx.x * 256;
  const int c2 = tid >> 4;
  const int vgb = tid & 15;
#pragma unroll
  for (int p = 0; p < 4; ++p) {
    int vox = (vgb + p * 16) * 4;
    const float4 a = *(const float4*)(src + (long)(2 * c2) * GV + vb + vox);
    const float4 b = *(const float4*)(src + (long)(2 * c2 + 1) * GV + vb + vox);
    tile[(vox + 0) * 17 + c2] = pkbf(a.x, b.x);
    tile[(vox + 1) * 17 + c2] = pkbf(a.y, b.y);
    tile[(vox + 2) * 17 + c2] = pkbf(a.z, b.z);
    tile[(vox + 3) * 17 + c2] = pkbf(a.w, b.w);
  }
  __syncthreads();
  const int vox2 = tid >> 2;
  const int c4 = (tid & 3) * 4;
#pragma unroll
  for (int j = 0; j < 4; ++j) {
    int vx = vox2 + j * 64;
    uint4 w;
    w.x = tile[vx * 17 + c4 + 0];
    w.y = tile[vx * 17 + c4 + 1];
    w.z = tile[vx * 17 + c4 + 2];
    w.w = tile[vx * 17 + c4 + 3];
    *(uint4*)(dst + (vb + vx) * 16 + c4) = w;
  }
}

// ---------------- fused main kernel ----------------
// K-order REORDERED: k=0..31 -> grid feats (W0 col 36+k); k=32..67 -> posenc dim k-32.
// LDS: [0,24576) B0 frags | [24576,57344) B1 frags | [57344,58880) b0/b1/w2 |
//      [58880,157184) per-wave scratch 8192 B x 12 (A0 frags / h0 frags overlap)
template <bool TA>
__global__ __launch_bounds__(NTHR, 3) void k_fvsrn(
    const float* __restrict__ X, const float* __restrict__ gridF,
    const unsigned short* __restrict__ gridT,
    const float* __restrict__ W0, const float* __restrict__ B0,
    const float* __restrict__ W1, const float* __restrict__ B1,
    const float* __restrict__ W2, const float* __restrict__ B2,
    float* __restrict__ out) {
  extern __shared__ char smem[];
  float* lb0 = (float*)(smem + 57344);
  float* lb1 = (float*)(smem + 57856);
  float* lw2 = (float*)(smem + 58368);
  const int tid = threadIdx.x;

  // --- build weight B-fragments in LDS (once per block)
  for (int idx = tid; idx < 56 * 64; idx += NTHR) {
    int f = idx >> 6;
    int L = idx & 63;
    int qq = L >> 4, lnn = L & 15;
    float vals[8];
    if (f < 24) {
      int kt = f >> 3, nt = f & 7;
      int n = nt * 16 + lnn;
      int kb = kt * 32 + qq * 8;
#pragma unroll
      for (int j = 0; j < 8; ++j) {
        int k = kb + j;
        float w = 0.f;
        if (k < 32) w = W0[n * DIN + 36 + k];
        else if (k < DIN) w = W0[n * DIN + (k - 32)];
        vals[j] = w;
      }
    } else {
      int g = f - 24;
      int kt = g >> 3, nt = g & 7;
      int n = nt * 16 + lnn;
      int kb = kt * 32 + qq * 8;
#pragma unroll
      for (int j = 0; j < 8; ++j) vals[j] = W1[n * HD + kb + j];
    }
    uint4 pk;
    pk.x = pkbf(vals[0], vals[1]);
    pk.y = pkbf(vals[2], vals[3]);
    pk.z = pkbf(vals[4], vals[5]);
    pk.w = pkbf(vals[6], vals[7]);
    *(uint4*)(smem + f * 1024 + L * 16) = pk;
  }
  if (tid < 128) lb0[tid] = B0[tid];
  else if (tid < 256) lb1[tid - 128] = B1[tid - 128];
  else if (tid < 384) lw2[tid - 256] = W2[tid - 256];
  __syncthreads();

  const int wave = tid >> 6, lane = tid & 63;
  char* scr = smem + 58880 + wave * 8192;
  const int q = lane >> 4, ln = lane & 15;     // MFMA-phase roles
  const int half = lane >> 5, pt = lane & 31;  // gather-phase roles (2 lanes/pt)
  const int mtg = pt >> 4, pmg = pt & 15;
  const float b2s = B2[0];

  int t = blockIdx.x * 12 + wave;
  unsigned p3 = ((unsigned)t * TILE_PTS + pt) * 3u;
  float px = X[p3], py = X[p3 + 1], pz = X[p3 + 2];

  uint4 cg[16];  // in-flight corner data for the *current* tile (8 corners x 32B)

  auto corner_issue = [&](float cx, float cy, float cz) {
    float fx = (cx + 1.f) * 0.5f * (GS - 1);
    float fy = (cy + 1.f) * 0.5f * (GS - 1);
    float fz = (cz + 1.f) * 0.5f * (GS - 1);
    int jx = (int)floorf(fx), jy = (int)floorf(fy), jz = (int)floorf(fz);
    int ix0 = min(max(jx, 0), GS - 1), ix1 = min(max(jx + 1, 0), GS - 1);
    int iy0 = min(max(jy, 0), GS - 1), iy1 = min(max(jy + 1, 0), GS - 1);
    int iz0 = min(max(jz, 0), GS - 1), iz1 = min(max(jz + 1, 0), GS - 1);
    unsigned zy[4];
    zy[0] = ((unsigned)(iz0 * GS + iy0)) * GS;
    zy[1] = ((unsigned)(iz0 * GS + iy1)) * GS;
    zy[2] = ((unsigned)(iz1 * GS + iy0)) * GS;
    zy[3] = ((unsigned)(iz1 * GS + iy1)) * GS;
    unsigned hb = (unsigned)(half << 4);
#pragma unroll
    for (int c = 0; c < 4; ++c) {
      unsigned o0 = ((zy[c] + (unsigned)ix0) << 5) + hb;
      unsigned o1 = ((zy[c] + (unsigned)ix1) << 5) + hb;
      const uint4* g0 = (const uint4*)(gridT + o0);
      const uint4* g1 = (const uint4*)(gridT + o1);
      cg[4 * c + 0] = g0[0];
      cg[4 * c + 1] = g0[1];
      cg[4 * c + 2] = g1[0];
      cg[4 * c + 3] = g1[1];
    }
  };
  if constexpr (TA) corner_issue(px, py, pz);

  for (; t < NTILES;) {
    const int tn = t + WAVES_TOT;
    const unsigned p0 = (unsigned)t * TILE_PTS;

    // ---- prefetch next tile's coords (latency overlapped with posenc/blend)
    float nx = px, ny = py, nz = pz;
    if (tn < NTILES) {
      unsigned np3 = ((unsigned)tn * TILE_PTS + pt) * 3u;
      nx = X[np3]; ny = X[np3 + 1]; nz = X[np3 + 2];
    }

    // ---- posenc ladder (full 36 dims; 2x redundant across halves)
    float v36[36];
    {
      const float PIf = 3.14159265358979f;
      float cc[3] = {px, py, pz};
#pragma unroll
      for (int ax = 0; ax < 3; ++ax) {
        float s, co;
        __sincosf(PIf * cc[ax], &s, &co);
#pragma unroll
        for (int i = 0; i < 6; ++i) {
          v36[i * 6 + ax] = s;
          v36[i * 6 + 3 + ax] = co;
          float s2 = 2.f * s * co;
          co = 1.f - 2.f * s * s;
          s = s2;
        }
      }
    }
    unsigned int pd[8], e0, e1;
    if (half == 0) {
#pragma unroll
      for (int d = 0; d < 8; ++d) pd[d] = pkbf(v36[2 * d], v36[2 * d + 1]);
      e0 = pkbf(v36[32], v36[33]);
      e1 = pkbf(v36[34], v36[35]);
    } else {
#pragma unroll
      for (int d = 0; d < 8; ++d) pd[d] = pkbf(v36[16 + 2 * d], v36[17 + 2 * d]);
      e0 = 0u; e1 = 0u;
    }

    // ---- blend: consume in-flight corner data (issued last iteration)
    f32x2 f2[8];
#pragma unroll
    for (int i = 0; i < 8; ++i) f2[i] = (f32x2){0.f, 0.f};
    {
      float fx = (px + 1.f) * 0.5f * (GS - 1);
      float fy = (py + 1.f) * 0.5f * (GS - 1);
      float fz = (pz + 1.f) * 0.5f * (GS - 1);
      float wx = fx - floorf(fx), wy = fy - floorf(fy), wz = fz - floorf(fz);
      float wxa[2] = {1.f - wx, wx};
      float wya[2] = {1.f - wy, wy};
      float wza[2] = {1.f - wz, wz};
      if constexpr (TA) {
#pragma unroll
        for (int c = 0; c < 8; ++c) {
          // c = zi*4 + yi*2 + xi  (matches corner_issue order: cg[4*(zi*2+yi) + xi*2 ..])
          int zi = c >> 2, yi = (c >> 1) & 1, xi = c & 1;
          float w = wza[zi] * wya[yi] * wxa[xi];
          f32x2 w2 = {w, w};
          uint4 g0 = cg[4 * (zi * 2 + yi) + xi * 2 + 0];
          uint4 g1 = cg[4 * (zi * 2 + yi) + xi * 2 + 1];
#define ACC_PAIR(u, i)                                                     \
  {                                                                        \
    f32x2 u2 = {__uint_as_float((u) << 16),                                \
                __uint_as_float((u) & 0xffff0000u)};                       \
    f2[i] = __builtin_elementwise_fma(u2, w2, f2[i]);                      \
  }
          ACC_PAIR(g0.x, 0) ACC_PAIR(g0.y, 1) ACC_PAIR(g0.z, 2) ACC_PAIR(g0.w, 3)
          ACC_PAIR(g1.x, 4) ACC_PAIR(g1.y, 5) ACC_PAIR(g1.z, 6) ACC_PAIR(g1.w, 7)
#undef ACC_PAIR
        }
      } else {
        int jx = (int)floorf(fx), jy = (int)floorf(fy), jz = (int)floorf(fz);
        int ix0 = min(max(jx, 0), GS - 1), ix1 = min(max(jx + 1, 0), GS - 1);
        int iy0 = min(max(jy, 0), GS - 1), iy1 = min(max(jy + 1, 0), GS - 1);
        int iz0 = min(max(jz, 0), GS - 1), iz1 = min(max(jz + 1, 0), GS - 1);
        int ixa[2] = {ix0, ix1}, iya[2] = {iy0, iy1}, iza[2] = {iz0, iz1};
#pragma unroll
        for (int c = 0; c < 8; ++c) {
          int zi = c >> 2, yi = (c >> 1) & 1, xi = c & 1;
          float w = wza[zi] * wya[yi] * wxa[xi];
          f32x2 w2 = {w, w};
          long vi = ((long)iza[zi] * GS + iya[yi]) * GS + ixa[xi];
#pragma unroll
          for (int i = 0; i < 8; ++i) {
            int ch = 16 * half + 2 * i;
            f32x2 u2 = {gridF[(long)ch * GV + vi], gridF[(long)(ch + 1) * GV + vi]};
            f2[i] = __builtin_elementwise_fma(u2, w2, f2[i]);
          }
        }
      }
    }

    // ---- issue next tile's corner loads NOW (land during MFMA phases)
    if constexpr (TA) {
      if (tn < NTILES) corner_issue(nx, ny, nz);
    }

    // ---- A0 fragment stores (6 aligned b128 per lane)
    {
      char* fbase = scr + (mtg * 3) * 1024;
      int ro = pmg * 16;
      uint4 s;
      s.x = pkbf(f2[0].x, f2[0].y); s.y = pkbf(f2[1].x, f2[1].y);
      s.z = pkbf(f2[2].x, f2[2].y); s.w = pkbf(f2[3].x, f2[3].y);
      *(uint4*)(fbase + (2 * half) * 256 + ro) = s;
      s.x = pkbf(f2[4].x, f2[4].y); s.y = pkbf(f2[5].x, f2[5].y);
      s.z = pkbf(f2[6].x, f2[6].y); s.w = pkbf(f2[7].x, f2[7].y);
      *(uint4*)(fbase + (2 * half + 1) * 256 + ro) = s;
      s.x = pd[0]; s.y = pd[1]; s.z = pd[2]; s.w = pd[3];
      *(uint4*)(fbase + 1024 + (2 * half) * 256 + ro) = s;
      s.x = pd[4]; s.y = pd[5]; s.z = pd[6]; s.w = pd[7];
      *(uint4*)(fbase + 1024 + (2 * half + 1) * 256 + ro) = s;
      s.x = e0; s.y = e1; s.z = 0u; s.w = 0u;
      *(uint4*)(fbase + 2048 + (2 * half) * 256 + ro) = s;
      s.x = 0u; s.y = 0u; s.z = 0u; s.w = 0u;
      *(uint4*)(fbase + 2048 + (2 * half + 1) * 256 + ro) = s;
    }
    __builtin_amdgcn_wave_barrier();  // wave-private LDS; DS pipe in-order per wave

    // ---- layer 0: h0 = relu(A0 * W0^T + b0)
    bf16x8 a0[6];
#pragma unroll
    for (int mt = 0; mt < 2; ++mt)
#pragma unroll
      for (int kt = 0; kt < 3; ++kt)
        a0[mt * 3 + kt] = *(const bf16x8*)(scr + (mt * 3 + kt) * 1024 + lane * 16);
    __builtin_amdgcn_wave_barrier();
#pragma unroll
    for (int nt = 0; nt < 8; ++nt) {
      float bn = lb0[nt * 16 + ln];
      f32x4 cinit = {bn, bn, bn, bn};
      f32x4 acc[2];
      acc[0] = cinit; acc[1] = cinit;
#pragma unroll
      for (int kt = 0; kt < 3; ++kt) {
        bf16x8 bfr = *(const bf16x8*)(smem + (kt * 8 + nt) * 1024 + lane * 16);
#pragma unroll
        for (int mt = 0; mt < 2; ++mt)
          acc[mt] = __builtin_amdgcn_mfma_f32_16x16x32_bf16(a0[mt * 3 + kt], bfr, acc[mt], 0, 0, 0);
      }
      // C-layout (col n=ln, row m=q*4+r) -> h0 A-frag-linear
      int n = nt * 16 + ln;
      int kt1 = n >> 5, j = n & 7, sub = (n >> 3) & 3;
#pragma unroll
      for (int mt = 0; mt < 2; ++mt)
#pragma unroll
        for (int r = 0; r < 4; r += 2) {
          unsigned pk2 = pkbf(fmaxf(acc[mt][r], 0.f), fmaxf(acc[mt][r + 1], 0.f));
          char* ba = scr + (mt * 4 + kt1) * 1024 + j * 2;
          *(unsigned short*)(ba + (sub * 16 + q * 4 + r) * 16) = (unsigned short)pk2;
          *(unsigned short*)(ba + (sub * 16 + q * 4 + r + 1) * 16) = (unsigned short)(pk2 >> 16);
        }
    }
    __builtin_amdgcn_wave_barrier();

    // ---- layer 1 + fused layer 2
    bf16x8 a1[8];
#pragma unroll
    for (int mt = 0; mt < 2; ++mt)
#pragma unroll
      for (int kt = 0; kt < 4; ++kt)
        a1[mt * 4 + kt] = *(const bf16x8*)(scr + (mt * 4 + kt) * 1024 + lane * 16);
    __builtin_amdgcn_wave_barrier();
    float y[8];
#pragma unroll
    for (int i = 0; i < 8; ++i) y[i] = 0.f;
#pragma unroll
    for (int nt = 0; nt < 8; ++nt) {
      float bn = lb1[nt * 16 + ln];
      float w2n = lw2[nt * 16 + ln];
      f32x4 cinit = {bn, bn, bn, bn};
      f32x4 acc[2];
      acc[0] = cinit; acc[1] = cinit;
#pragma unroll
      for (int kt = 0; kt < 4; ++kt) {
        bf16x8 bfr = *(const bf16x8*)(smem + 24576 + (kt * 8 + nt) * 1024 + lane * 16);
#pragma unroll
        for (int mt = 0; mt < 2; ++mt)
          acc[mt] = __builtin_amdgcn_mfma_f32_16x16x32_bf16(a1[mt * 4 + kt], bfr, acc[mt], 0, 0, 0);
      }
#pragma unroll
      for (int mt = 0; mt < 2; ++mt)
#pragma unroll
        for (int r = 0; r < 4; ++r)
          y[mt * 4 + r] += w2n * fmaxf(acc[mt][r], 0.f);
    }
#pragma unroll
    for (int i = 0; i < 8; ++i) {
      float v = y[i];
      v += __shfl_xor(v, 1);
      v += __shfl_xor(v, 2);
      v += __shfl_xor(v, 4);
      v += __shfl_xor(v, 8);
      y[i] = v;
    }
    if (ln == 0) {
#pragma unroll
      for (int mt = 0; mt < 2; ++mt)
#pragma unroll
        for (int r = 0; r < 4; ++r)
          out[p0 + mt * 16 + q * 4 + r] = (y[mt * 4 + r] + b2s) * 2.f - 1.f;
    }
    px = nx; py = ny; pz = nz;
    t = tn;
  }
}

extern "C" void kernel_launch(void* const* d_in, const int* in_sizes, int n_in,
                              void* d_out, int out_size, void* d_ws, size_t ws_size,
                              hipStream_t stream) {
  const float* X  = (const float*)d_in[0];
  const float* G  = (const float*)d_in[1];
  const float* W0 = (const float*)d_in[2];
  const float* B0 = (const float*)d_in[3];
  const float* W1 = (const float*)d_in[4];
  const float* B1 = (const float*)d_in[5];
  const float* W2 = (const float*)d_in[6];
  const float* B2 = (const float*)d_in[7];
  float* out = (float*)d_out;

  const size_t needT = (size_t)GV * NCH * 2;  // 56.6 MB transposed bf16 grid
  const size_t shmem = 157184;

  if (ws_size >= needT) {
    k_prep_grid<<<GV / 256, 256, 0, stream>>>(G, (unsigned int*)d_ws);
    k_fvsrn<true><<<NBLK, NTHR, shmem, stream>>>(
        X, G, (const unsigned short*)d_ws, W0, B0, W1, B1, W2, B2, out);
  } else {
    k_fvsrn<false><<<NBLK, NTHR, shmem, stream>>>(
        X, G, (const unsigned short*)nullptr, W0, B0, W1, B1, W2, B2, out);
  }
}

// Round 5
// 416.015 us; speedup vs baseline: 1.0711x; 1.0711x over previous
//
#include <hip/hip_runtime.h>

#define NPTS 1048576
#define NCH 32
#define GS 96
#define GV (GS * GS * GS)
#define DIN 68
#define HD 128
#define TILE_PTS 32
#define NTILES (NPTS / TILE_PTS)   // 32768 exact, no tail
#define NBLK 256
#define NTHR 768                   // 12 waves/block, 1 block/CU -> 3 waves/SIMD
#define WAVES_TOT (NBLK * 12)

typedef __bf16 bf16x8 __attribute__((ext_vector_type(8)));
typedef float f32x4 __attribute__((ext_vector_type(4)));
typedef float f32x2 __attribute__((ext_vector_type(2)));

__device__ __forceinline__ unsigned int f2bf(float f) {
  unsigned int u = __float_as_uint(f);
  return (u + 0x7fffu + ((u >> 16) & 1u)) >> 16;  // RNE
}
__device__ __forceinline__ unsigned int pkbf(float a, float b) {
#if __has_builtin(__builtin_amdgcn_cvt_pk_bf16_f32)
  return __builtin_bit_cast(unsigned int, __builtin_amdgcn_cvt_pk_bf16_f32(a, b));
#else
  return f2bf(a) | (f2bf(b) << 16);
#endif
}

// ---------------- grid transpose: [32][96^3] f32 -> [96^3][32] bf16 ----------------
__global__ __launch_bounds__(256) void k_prep_grid(const float* __restrict__ src,
                                                   unsigned int* __restrict__ dst) {
  __shared__ unsigned int tile[256 * 17];
  const int tid = threadIdx.x;
  const long vb = (long)blockIdx.x * 256;
  const int c2 = tid >> 4;
  const int vgb = tid & 15;
#pragma unroll
  for (int p = 0; p < 4; ++p) {
    int vox = (vgb + p * 16) * 4;
    const float4 a = *(const float4*)(src + (long)(2 * c2) * GV + vb + vox);
    const float4 b = *(const float4*)(src + (long)(2 * c2 + 1) * GV + vb + vox);
    tile[(vox + 0) * 17 + c2] = pkbf(a.x, b.x);
    tile[(vox + 1) * 17 + c2] = pkbf(a.y, b.y);
    tile[(vox + 2) * 17 + c2] = pkbf(a.z, b.z);
    tile[(vox + 3) * 17 + c2] = pkbf(a.w, b.w);
  }
  __syncthreads();
  const int vox2 = tid >> 2;
  const int c4 = (tid & 3) * 4;
#pragma unroll
  for (int j = 0; j < 4; ++j) {
    int vx = vox2 + j * 64;
    uint4 w;
    w.x = tile[vx * 17 + c4 + 0];
    w.y = tile[vx * 17 + c4 + 1];
    w.z = tile[vx * 17 + c4 + 2];
    w.w = tile[vx * 17 + c4 + 3];
    *(uint4*)(dst + (vb + vx) * 16 + c4) = w;
  }
}

// ---------------- fused main kernel ----------------
// K-order REORDERED: k=0..31 -> grid feats (W0 col 36+k); k=32..67 -> posenc dim k-32.
// LDS: [0,24576) B0 frags | [24576,57344) B1 frags | [57344,58880) b0/b1/w2 |
//      [58880,157184) per-wave scratch 8192 B x 12 (A0 frags / h0 frags overlap)
template <bool TA>
__global__ __launch_bounds__(NTHR, 3) void k_fvsrn(
    const float* __restrict__ X, const float* __restrict__ gridF,
    const unsigned short* __restrict__ gridT,
    const float* __restrict__ W0, const float* __restrict__ B0,
    const float* __restrict__ W1, const float* __restrict__ B1,
    const float* __restrict__ W2, const float* __restrict__ B2,
    float* __restrict__ out) {
  extern __shared__ char smem[];
  float* lb0 = (float*)(smem + 57344);
  float* lb1 = (float*)(smem + 57856);
  float* lw2 = (float*)(smem + 58368);
  const int tid = threadIdx.x;

  // --- build weight B-fragments in LDS (once per block)
  for (int idx = tid; idx < 56 * 64; idx += NTHR) {
    int f = idx >> 6;
    int L = idx & 63;
    int qq = L >> 4, lnn = L & 15;
    float vals[8];
    if (f < 24) {
      int kt = f >> 3, nt = f & 7;
      int n = nt * 16 + lnn;
      int kb = kt * 32 + qq * 8;
#pragma unroll
      for (int j = 0; j < 8; ++j) {
        int k = kb + j;
        float w = 0.f;
        if (k < 32) w = W0[n * DIN + 36 + k];
        else if (k < DIN) w = W0[n * DIN + (k - 32)];
        vals[j] = w;
      }
    } else {
      int g = f - 24;
      int kt = g >> 3, nt = g & 7;
      int n = nt * 16 + lnn;
      int kb = kt * 32 + qq * 8;
#pragma unroll
      for (int j = 0; j < 8; ++j) vals[j] = W1[n * HD + kb + j];
    }
    uint4 pk;
    pk.x = pkbf(vals[0], vals[1]);
    pk.y = pkbf(vals[2], vals[3]);
    pk.z = pkbf(vals[4], vals[5]);
    pk.w = pkbf(vals[6], vals[7]);
    *(uint4*)(smem + f * 1024 + L * 16) = pk;
  }
  if (tid < 128) lb0[tid] = B0[tid];
  else if (tid < 256) lb1[tid - 128] = B1[tid - 128];
  else if (tid < 384) lw2[tid - 256] = W2[tid - 256];
  __syncthreads();

  const int wave = tid >> 6, lane = tid & 63;
  char* scr = smem + 58880 + wave * 8192;
  const int q = lane >> 4, ln = lane & 15;     // MFMA-phase roles
  const int half = lane >> 5, pt = lane & 31;  // gather-phase roles (2 lanes/pt)
  const int mtg = pt >> 4, pmg = pt & 15;
  const unsigned hb = (unsigned)(half << 4);
  const float b2s = B2[0];

  int t = blockIdx.x * 12 + wave;
  unsigned p3 = ((unsigned)t * TILE_PTS + pt) * 3u;
  float px = X[p3], py = X[p3 + 1], pz = X[p3 + 2];

  // in-flight corner data: 8 corners x 2 x uint4, as NAMED locals (no array ->
  // no scratch lowering; R4's cg[16] array was spilled: WRITE_SIZE 4->595 MB)
  uint4 g0a, g0b, g1a, g1b, g2a, g2b, g3a, g3b;
  uint4 g4a, g4b, g5a, g5b, g6a, g6b, g7a, g7b;

  // corner index c = zi*4 + yi*2 + xi
#define CORNER_ISSUE(cx, cy, cz)                                            \
  do {                                                                      \
    float fx = ((cx) + 1.f) * 0.5f * (GS - 1);                              \
    float fy = ((cy) + 1.f) * 0.5f * (GS - 1);                              \
    float fz = ((cz) + 1.f) * 0.5f * (GS - 1);                              \
    int jx = (int)floorf(fx), jy = (int)floorf(fy), jz = (int)floorf(fz);   \
    int ix0 = min(max(jx, 0), GS - 1), ix1 = min(max(jx + 1, 0), GS - 1);   \
    int iy0 = min(max(jy, 0), GS - 1), iy1 = min(max(jy + 1, 0), GS - 1);   \
    int iz0 = min(max(jz, 0), GS - 1), iz1 = min(max(jz + 1, 0), GS - 1);   \
    unsigned zy00 = ((unsigned)(iz0 * GS + iy0)) * GS;                      \
    unsigned zy01 = ((unsigned)(iz0 * GS + iy1)) * GS;                      \
    unsigned zy10 = ((unsigned)(iz1 * GS + iy0)) * GS;                      \
    unsigned zy11 = ((unsigned)(iz1 * GS + iy1)) * GS;                      \
    const uint4* P;                                                         \
    P = (const uint4*)(gridT + (((zy00 + (unsigned)ix0) << 5) + hb));       \
    g0a = P[0]; g0b = P[1];                                                 \
    P = (const uint4*)(gridT + (((zy00 + (unsigned)ix1) << 5) + hb));       \
    g1a = P[0]; g1b = P[1];                                                 \
    P = (const uint4*)(gridT + (((zy01 + (unsigned)ix0) << 5) + hb));       \
    g2a = P[0]; g2b = P[1];                                                 \
    P = (const uint4*)(gridT + (((zy01 + (unsigned)ix1) << 5) + hb));       \
    g3a = P[0]; g3b = P[1];                                                 \
    P = (const uint4*)(gridT + (((zy10 + (unsigned)ix0) << 5) + hb));       \
    g4a = P[0]; g4b = P[1];                                                 \
    P = (const uint4*)(gridT + (((zy10 + (unsigned)ix1) << 5) + hb));       \
    g5a = P[0]; g5b = P[1];                                                 \
    P = (const uint4*)(gridT + (((zy11 + (unsigned)ix0) << 5) + hb));       \
    g6a = P[0]; g6b = P[1];                                                 \
    P = (const uint4*)(gridT + (((zy11 + (unsigned)ix1) << 5) + hb));       \
    g7a = P[0]; g7b = P[1];                                                 \
  } while (0)

  if constexpr (TA) CORNER_ISSUE(px, py, pz);

  for (; t < NTILES;) {
    const int tn = t + WAVES_TOT;
    const unsigned p0 = (unsigned)t * TILE_PTS;

    // ---- prefetch next tile's coords
    float nx = px, ny = py, nz = pz;
    if (tn < NTILES) {
      unsigned np3 = ((unsigned)tn * TILE_PTS + pt) * 3u;
      nx = X[np3]; ny = X[np3 + 1]; nz = X[np3 + 2];
    }

    // ---- posenc ladder (full 36 dims; 2x redundant across halves)
    float v36[36];
    {
      const float PIf = 3.14159265358979f;
      float cc[3] = {px, py, pz};
#pragma unroll
      for (int ax = 0; ax < 3; ++ax) {
        float s, co;
        __sincosf(PIf * cc[ax], &s, &co);
#pragma unroll
        for (int i = 0; i < 6; ++i) {
          v36[i * 6 + ax] = s;
          v36[i * 6 + 3 + ax] = co;
          float s2 = 2.f * s * co;
          co = 1.f - 2.f * s * s;
          s = s2;
        }
      }
    }
    unsigned int pd[8], e0, e1;
    if (half == 0) {
#pragma unroll
      for (int d = 0; d < 8; ++d) pd[d] = pkbf(v36[2 * d], v36[2 * d + 1]);
      e0 = pkbf(v36[32], v36[33]);
      e1 = pkbf(v36[34], v36[35]);
    } else {
#pragma unroll
      for (int d = 0; d < 8; ++d) pd[d] = pkbf(v36[16 + 2 * d], v36[17 + 2 * d]);
      e0 = 0u; e1 = 0u;
    }

    // ---- blend: consume in-flight corner data (issued previous iteration)
    f32x2 f2[8];
#pragma unroll
    for (int i = 0; i < 8; ++i) f2[i] = (f32x2){0.f, 0.f};
    {
      float fx = (px + 1.f) * 0.5f * (GS - 1);
      float fy = (py + 1.f) * 0.5f * (GS - 1);
      float fz = (pz + 1.f) * 0.5f * (GS - 1);
      float wx = fx - floorf(fx), wy = fy - floorf(fy), wz = fz - floorf(fz);
      float ox = 1.f - wx, oy = 1.f - wy, oz = 1.f - wz;
      if constexpr (TA) {
#define ACC_PAIR(u, i)                                                     \
  {                                                                        \
    f32x2 u2 = {__uint_as_float((u) << 16),                                \
                __uint_as_float((u) & 0xffff0000u)};                       \
    f2[i] = __builtin_elementwise_fma(u2, w2, f2[i]);                      \
  }
#define BLEND_CORNER(ga, gb, wexpr)                                        \
  {                                                                        \
    float w = (wexpr);                                                     \
    f32x2 w2 = {w, w};                                                     \
    ACC_PAIR(ga.x, 0) ACC_PAIR(ga.y, 1) ACC_PAIR(ga.z, 2) ACC_PAIR(ga.w, 3) \
    ACC_PAIR(gb.x, 4) ACC_PAIR(gb.y, 5) ACC_PAIR(gb.z, 6) ACC_PAIR(gb.w, 7) \
  }
        BLEND_CORNER(g0a, g0b, oz * oy * ox)
        BLEND_CORNER(g1a, g1b, oz * oy * wx)
        BLEND_CORNER(g2a, g2b, oz * wy * ox)
        BLEND_CORNER(g3a, g3b, oz * wy * wx)
        BLEND_CORNER(g4a, g4b, wz * oy * ox)
        BLEND_CORNER(g5a, g5b, wz * oy * wx)
        BLEND_CORNER(g6a, g6b, wz * wy * ox)
        BLEND_CORNER(g7a, g7b, wz * wy * wx)
#undef BLEND_CORNER
#undef ACC_PAIR
      } else {
        int jx = (int)floorf(fx), jy = (int)floorf(fy), jz = (int)floorf(fz);
        int ix0 = min(max(jx, 0), GS - 1), ix1 = min(max(jx + 1, 0), GS - 1);
        int iy0 = min(max(jy, 0), GS - 1), iy1 = min(max(jy + 1, 0), GS - 1);
        int iz0 = min(max(jz, 0), GS - 1), iz1 = min(max(jz + 1, 0), GS - 1);
        int ixa[2] = {ix0, ix1}, iya[2] = {iy0, iy1}, iza[2] = {iz0, iz1};
        float wxa[2] = {ox, wx}, wya[2] = {oy, wy}, wza[2] = {oz, wz};
#pragma unroll
        for (int c = 0; c < 8; ++c) {
          int zi = c >> 2, yi = (c >> 1) & 1, xi = c & 1;
          float w = wza[zi] * wya[yi] * wxa[xi];
          f32x2 w2 = {w, w};
          long vi = ((long)iza[zi] * GS + iya[yi]) * GS + ixa[xi];
#pragma unroll
          for (int i = 0; i < 8; ++i) {
            int ch = 16 * half + 2 * i;
            f32x2 u2 = {gridF[(long)ch * GV + vi], gridF[(long)(ch + 1) * GV + vi]};
            f2[i] = __builtin_elementwise_fma(u2, w2, f2[i]);
          }
        }
      }
    }

    // ---- issue next tile's corner loads NOW (land during MFMA phases)
    if constexpr (TA) {
      if (tn < NTILES) CORNER_ISSUE(nx, ny, nz);
    }

    // ---- A0 fragment stores (6 aligned b128 per lane)
    {
      char* fbase = scr + (mtg * 3) * 1024;
      int ro = pmg * 16;
      uint4 s;
      s.x = pkbf(f2[0].x, f2[0].y); s.y = pkbf(f2[1].x, f2[1].y);
      s.z = pkbf(f2[2].x, f2[2].y); s.w = pkbf(f2[3].x, f2[3].y);
      *(uint4*)(fbase + (2 * half) * 256 + ro) = s;
      s.x = pkbf(f2[4].x, f2[4].y); s.y = pkbf(f2[5].x, f2[5].y);
      s.z = pkbf(f2[6].x, f2[6].y); s.w = pkbf(f2[7].x, f2[7].y);
      *(uint4*)(fbase + (2 * half + 1) * 256 + ro) = s;
      s.x = pd[0]; s.y = pd[1]; s.z = pd[2]; s.w = pd[3];
      *(uint4*)(fbase + 1024 + (2 * half) * 256 + ro) = s;
      s.x = pd[4]; s.y = pd[5]; s.z = pd[6]; s.w = pd[7];
      *(uint4*)(fbase + 1024 + (2 * half + 1) * 256 + ro) = s;
      s.x = e0; s.y = e1; s.z = 0u; s.w = 0u;
      *(uint4*)(fbase + 2048 + (2 * half) * 256 + ro) = s;
      s.x = 0u; s.y = 0u; s.z = 0u; s.w = 0u;
      *(uint4*)(fbase + 2048 + (2 * half + 1) * 256 + ro) = s;
    }
    __builtin_amdgcn_wave_barrier();  // wave-private LDS; DS pipe in-order per wave

    // ---- layer 0: h0 = relu(A0 * W0^T + b0)
    bf16x8 a0[6];
#pragma unroll
    for (int mt = 0; mt < 2; ++mt)
#pragma unroll
      for (int kt = 0; kt < 3; ++kt)
        a0[mt * 3 + kt] = *(const bf16x8*)(scr + (mt * 3 + kt) * 1024 + lane * 16);
    __builtin_amdgcn_wave_barrier();
#pragma unroll
    for (int nt = 0; nt < 8; ++nt) {
      float bn = lb0[nt * 16 + ln];
      f32x4 cinit = {bn, bn, bn, bn};
      f32x4 acc[2];
      acc[0] = cinit; acc[1] = cinit;
#pragma unroll
      for (int kt = 0; kt < 3; ++kt) {
        bf16x8 bfr = *(const bf16x8*)(smem + (kt * 8 + nt) * 1024 + lane * 16);
#pragma unroll
        for (int mt = 0; mt < 2; ++mt)
          acc[mt] = __builtin_amdgcn_mfma_f32_16x16x32_bf16(a0[mt * 3 + kt], bfr, acc[mt], 0, 0, 0);
      }
      // C-layout (col n=ln, row m=q*4+r) -> h0 A-frag-linear
      int n = nt * 16 + ln;
      int kt1 = n >> 5, j = n & 7, sub = (n >> 3) & 3;
#pragma unroll
      for (int mt = 0; mt < 2; ++mt)
#pragma unroll
        for (int r = 0; r < 4; r += 2) {
          unsigned pk2 = pkbf(fmaxf(acc[mt][r], 0.f), fmaxf(acc[mt][r + 1], 0.f));
          char* ba = scr + (mt * 4 + kt1) * 1024 + j * 2;
          *(unsigned short*)(ba + (sub * 16 + q * 4 + r) * 16) = (unsigned short)pk2;
          *(unsigned short*)(ba + (sub * 16 + q * 4 + r + 1) * 16) = (unsigned short)(pk2 >> 16);
        }
    }
    __builtin_amdgcn_wave_barrier();

    // ---- layer 1 + fused layer 2
    bf16x8 a1[8];
#pragma unroll
    for (int mt = 0; mt < 2; ++mt)
#pragma unroll
      for (int kt = 0; kt < 4; ++kt)
        a1[mt * 4 + kt] = *(const bf16x8*)(scr + (mt * 4 + kt) * 1024 + lane * 16);
    __builtin_amdgcn_wave_barrier();
    float y[8];
#pragma unroll
    for (int i = 0; i < 8; ++i) y[i] = 0.f;
#pragma unroll
    for (int nt = 0; nt < 8; ++nt) {
      float bn = lb1[nt * 16 + ln];
      float w2n = lw2[nt * 16 + ln];
      f32x4 cinit = {bn, bn, bn, bn};
      f32x4 acc[2];
      acc[0] = cinit; acc[1] = cinit;
#pragma unroll
      for (int kt = 0; kt < 4; ++kt) {
        bf16x8 bfr = *(const bf16x8*)(smem + 24576 + (kt * 8 + nt) * 1024 + lane * 16);
#pragma unroll
        for (int mt = 0; mt < 2; ++mt)
          acc[mt] = __builtin_amdgcn_mfma_f32_16x16x32_bf16(a1[mt * 4 + kt], bfr, acc[mt], 0, 0, 0);
      }
#pragma unroll
      for (int mt = 0; mt < 2; ++mt)
#pragma unroll
        for (int r = 0; r < 4; ++r)
          y[mt * 4 + r] += w2n * fmaxf(acc[mt][r], 0.f);
    }
#pragma unroll
    for (int i = 0; i < 8; ++i) {
      float v = y[i];
      v += __shfl_xor(v, 1);
      v += __shfl_xor(v, 2);
      v += __shfl_xor(v, 4);
      v += __shfl_xor(v, 8);
      y[i] = v;
    }
    if (ln == 0) {
#pragma unroll
      for (int mt = 0; mt < 2; ++mt)
#pragma unroll
        for (int r = 0; r < 4; ++r)
          out[p0 + mt * 16 + q * 4 + r] = (y[mt * 4 + r] + b2s) * 2.f - 1.f;
    }
    px = nx; py = ny; pz = nz;
    t = tn;
  }
#undef CORNER_ISSUE
}

extern "C" void kernel_launch(void* const* d_in, const int* in_sizes, int n_in,
                              void* d_out, int out_size, void* d_ws, size_t ws_size,
                              hipStream_t stream) {
  const float* X  = (const float*)d_in[0];
  const float* G  = (const float*)d_in[1];
  const float* W0 = (const float*)d_in[2];
  const float* B0 = (const float*)d_in[3];
  const float* W1 = (const float*)d_in[4];
  const float* B1 = (const float*)d_in[5];
  const float* W2 = (const float*)d_in[6];
  const float* B2 = (const float*)d_in[7];
  float* out = (float*)d_out;

  const size_t needT = (size_t)GV * NCH * 2;  // 56.6 MB transposed bf16 grid
  const size_t shmem = 157184;

  if (ws_size >= needT) {
    k_prep_grid<<<GV / 256, 256, 0, stream>>>(G, (unsigned int*)d_ws);
    k_fvsrn<true><<<NBLK, NTHR, shmem, stream>>>(
        X, G, (const unsigned short*)d_ws, W0, B0, W1, B1, W2, B2, out);
  } else {
    k_fvsrn<false><<<NBLK, NTHR, shmem, stream>>>(
        X, G, (const unsigned short*)nullptr, W0, B0, W1, B1, W2, B2, out);
  }
}